// Round 10
// baseline (403.819 us; speedup 1.0000x reference)
//
#include <hip/hip_runtime.h>
#include <stdint.h>
#include <stddef.h>

// RBF kernel: out[i][j] = exp(-max(||x_i||^2 + ||x1_j||^2 - 2*x_i.x1_j, 0) / 1.0)
// N = M = 8192, K = 512, fp32 in/out.
//
// Round 15 = streaming GEMM: R8's access shape (all blocks stream the same
// 4MB B array -> FETCH collapsed to 19.6MB, proven) driven by R3's DMA
// engine (global_load_lds + counted vmcnt ladder, proven rate). 256
// persistent blocks (1/CU forced by 96KB LDS), each owns 32 FULL output
// rows: A panel reg-resident (32 VGPR, loaded once), 128 B-tiles of 64
// x1-rows double-buffered in LDS, output staged in a 32KB slab and flushed
// every 4 tiles as 1KB-contiguous NT runs per row. Wait arithmetic: vmcnt(N)
// where N = count of YOUNGER in-flight vmem ops (5 steady: next tile's 4 DMA
// + 1 norm load; 9 right after a flush: +4 NT stores; 0 at the tail) -- tile
// i's data guaranteed complete, pipe never drained. Budget: B L2-reads
// 128MB/XCD @4.3TB/s = 30us || writes 264MB @6.4 = 41us || MFMA 15us.

#define NROWS 8192
#define DIMK  512

typedef __bf16 bf16x8 __attribute__((ext_vector_type(8)));
typedef int    i32x8  __attribute__((ext_vector_type(8)));
typedef int    i32x4  __attribute__((ext_vector_type(4)));
typedef float  f32x4  __attribute__((ext_vector_type(4)));

#define AS1 __attribute__((address_space(1)))
#define AS3 __attribute__((address_space(3)))

#define WAITV(n) asm volatile("s_waitcnt vmcnt(" #n ")" ::: "memory")
#define WAITL()  asm volatile("s_waitcnt lgkmcnt(0)" ::: "memory")
#define BAR()    asm volatile("s_barrier" ::: "memory")

__device__ __forceinline__ uint32_t f2bf(float f) {
    uint32_t u = __float_as_uint(f);
    return (u + 0x7FFFu + ((u >> 16) & 1u)) >> 16;
}

__device__ __forceinline__ uint32_t pk_fp8x4(float a, float b, float c, float d) {
    int w = __builtin_amdgcn_cvt_pk_fp8_f32(a, b, 0, false);
    w     = __builtin_amdgcn_cvt_pk_fp8_f32(c, d, w, true);
    return (uint32_t)w;
}

// assemble a 32B MFMA fragment from two (swizzle-permuted) 16B LDS chunks
__device__ __forceinline__ i32x8 ld_frag(const uint8_t* base, int c_lo, int c_hi) {
    i32x4 lo = *(const i32x4*)(base + c_lo);
    i32x4 hi = *(const i32x4*)(base + c_hi);
    i32x8 r;
    r[0] = lo[0]; r[1] = lo[1]; r[2] = lo[2]; r[3] = lo[3];
    r[4] = hi[0]; r[5] = hi[1]; r[6] = hi[2]; r[7] = hi[3];
    return r;
}

// ---------------------------------------------------------------- precast ---
__global__ __launch_bounds__(256) void precast_fp8(
    const float* __restrict__ x, const float* __restrict__ x1,
    uint8_t* __restrict__ xf, uint8_t* __restrict__ x1f,
    float* __restrict__ xsq, float* __restrict__ x1sq)
{
    const int w    = threadIdx.x >> 6;
    const int lane = threadIdx.x & 63;
    const int row  = blockIdx.x * 4 + w;
    const float* src;
    uint8_t* dstb;
    float* dsts;
    if (blockIdx.y == 0) { src = x  + (size_t)row * DIMK; dstb = xf  + (size_t)row * DIMK; dsts = xsq  + row; }
    else                 { src = x1 + (size_t)row * DIMK; dstb = x1f + (size_t)row * DIMK; dsts = x1sq + row; }

    float4 v0 = ((const float4*)src)[lane * 2];
    float4 v1 = ((const float4*)src)[lane * 2 + 1];
    float s = v0.x * v0.x + v0.y * v0.y + v0.z * v0.z + v0.w * v0.w
            + v1.x * v1.x + v1.y * v1.y + v1.z * v1.z + v1.w * v1.w;

    uint2 p;
    p.x = pk_fp8x4(v0.x, v0.y, v0.z, v0.w);
    p.y = pk_fp8x4(v1.x, v1.y, v1.z, v1.w);
    ((uint2*)dstb)[lane] = p;

    #pragma unroll
    for (int off = 32; off > 0; off >>= 1) s += __shfl_down(s, off);
    if (lane == 0) *dsts = s;
}

// norms only (fallback path)
__global__ __launch_bounds__(256) void norms_only(
    const float* __restrict__ x, const float* __restrict__ x1,
    float* __restrict__ xsq, float* __restrict__ x1sq)
{
    const int row = blockIdx.x;
    const float* src = (blockIdx.y == 0) ? x + (size_t)row * DIMK : x1 + (size_t)row * DIMK;
    float* dsts      = (blockIdx.y == 0) ? xsq + row : x1sq + row;
    const int t = threadIdx.x;
    float2 v = ((const float2*)src)[t];
    float s = v.x * v.x + v.y * v.y;
    #pragma unroll
    for (int off = 32; off > 0; off >>= 1) s += __shfl_down(s, off);
    __shared__ float red[4];
    if ((t & 63) == 0) red[t >> 6] = s;
    __syncthreads();
    if (t == 0) *dsts = red[0] + red[1] + red[2] + red[3];
}

// ------------------------------------ streaming GEMM (MX-fp8, DMA ladder) ---
// LDS: B buf0 [0,32K), B buf1 [32K,64K), out slab [64K,96K) = 96KB -> 1
// block/CU. Block b owns out rows [b*32, b*32+32). 8 waves (2 wm x 4 wn):
// wave computes out[wm*16+lrow][tile*64 + wn*16 + q*4 + r] per tile.
// Operand frag layout (proven R3/R8): row = lane&15, kbytes q*32..+32 per
// 128B K-slice; B staged with per-slice chunk swizzle k -> k^(row&7) via
// pre-swizzled DMA source (LDS dest linear); A reg-direct (no swizzle).
__global__ __launch_bounds__(512, 2) void rbf_stream_mxfp8(
    const uint8_t* __restrict__ Xf, const uint8_t* __restrict__ X1f,
    const float* __restrict__ xsq, const float* __restrict__ x1sq,
    float* __restrict__ out)
{
    __shared__ uint8_t lds[98304];

    const int t    = threadIdx.x;
    const int b    = blockIdx.x;               // out rows [b*32, b*32+32)
    const int lane = t & 63;
    const int w    = t >> 6;                   // 0..7
    const int wm   = w >> 2;                   // 0..1: 16-row half
    const int wn   = w & 3;                    // 0..3: 16-col group in tile
    const int lrow = lane & 15;
    const int q    = lane >> 4;                // 0..3
    const int s    = lrow & 7;
    const int c_lo = ((2 * q)     ^ s) * 16;
    const int c_hi = ((2 * q + 1) ^ s) * 16;

    // one-time: this lane's out-row norm + A fragments (reg-resident)
    const float xr = xsq[b * 32 + wm * 16 + lrow];
    const uint8_t* gA = Xf + (size_t)(b * 32 + wm * 16 + lrow) * DIMK + q * 32;
    i32x8 af[4];
    #pragma unroll
    for (int kt = 0; kt < 4; ++kt)
        af[kt] = *(const i32x8*)(gA + kt * 128);

    // stage B tile tl (64 x1-rows x 512B = 32KB) into buf bi: 4 DMA/thread,
    // linear LDS dest g*16, source pre-swizzled (chunk k of row r from
    // k^(r&7)) so LDS holds the R3-family swizzled layout.
    auto stage = [&](int tl, int bi) {
        const uint8_t* gB = X1f + (size_t)tl * 64 * DIMK;
        uint8_t* dst = &lds[bi * 32768];
        #pragma unroll
        for (int c = 0; c < 4; ++c) {
            const int g  = c * 512 + t;        // 16B chunk id 0..2047
            const int r  = g >> 5;             // B row 0..63
            const int kq = g & 31;             // chunk within row
            const int srcoff = r * DIMK + (kq & 24) * 16 + (((kq & 7) ^ (r & 7)) << 4);
            __builtin_amdgcn_global_load_lds((AS1 void*)(gB + srcoff),
                                             (AS3 void*)(dst + (size_t)g * 16), 16, 0, 0);
        }
    };

    // prologue: tiles 0,1 in flight; per-tile x1-norm vector rides along
    f32x4 x1_c = *(const f32x4*)&x1sq[0 * 64 + wn * 16 + q * 4];
    stage(0, 0);
    f32x4 x1_n = *(const f32x4*)&x1sq[1 * 64 + wn * 16 + q * 4];
    stage(1, 1);

    #pragma unroll 1
    for (int i = 0; i < 128; ++i) {
        // vmcnt(N) with N = count of YOUNGER in-flight vmem (in-order
        // retire => tile i's 4 DMA + norm load are guaranteed complete):
        // steady 5 (next tile), post-flush 9 (+4 NT stores), tail 0.
        if (i == 127)                   { WAITV(0); }
        else if ((i & 3) == 0 && i > 0) { WAITV(9); }
        else                            { WAITV(5); }
        BAR();

        const uint8_t* Bb = &lds[(i & 1) * 32768];
        i32x8 bg[4];
        #pragma unroll
        for (int kt = 0; kt < 4; ++kt)
            bg[kt] = ld_frag(Bb + (wn * 16 + lrow) * DIMK + kt * 128, c_lo, c_hi);

        WAITL(); BAR();                 // all waves done reading buf (i&1)

        f32x4 x1_nl = f32x4{0.f, 0.f, 0.f, 0.f};
        if (i < 126) {
            x1_nl = *(const f32x4*)&x1sq[(i + 2) * 64 + wn * 16 + q * 4];
            stage(i + 2, i & 1);
        }

        f32x4 acc = f32x4{0.f, 0.f, 0.f, 0.f};
        #pragma unroll
        for (int kt = 0; kt < 4; ++kt)
            acc = __builtin_amdgcn_mfma_scale_f32_16x16x128_f8f6f4(
                bg[kt], af[kt], acc,
                0, 0, 0, 0x7F7F7F7F, 0, 0x7F7F7F7F);

        // epilogue into slab: lane value = out[wm*16+lrow][.. + wn*16+q*4+r]
        f32x4 ev;
        #pragma unroll
        for (int r = 0; r < 4; ++r) {
            float d = fmaxf(xr + x1_c[r] - 2.0f * acc[r], 0.0f);
            ev[r] = __expf(-d);
        }
        const int c    = (i & 3) * 16 + wn * 4 + q;        // slab chunk 0..63
        const int chat = (c & ~7) | ((c & 7) ^ s);
        *(f32x4*)(&lds[65536 + (wm * 16 + lrow) * 1024 + chat * 16]) = ev;

        x1_c = x1_n; x1_n = x1_nl;

        if ((i & 3) == 3) {
            WAITL(); BAR();             // slab writes visible block-wide
            // flush 32 rows x 1KB contiguous NT runs; wave w -> rows w*4..+4
            float* gbase = out + (size_t)(b * 32) * NROWS + (i >> 2) * 256;
            #pragma unroll
            for (int si = 0; si < 4; ++si) {
                const int row   = w * 4 + si;
                const int chat2 = (lane & ~7) | ((lane & 7) ^ (row & 7));
                f32x4 v = *(const f32x4*)(&lds[65536 + row * 1024 + chat2 * 16]);
                __builtin_nontemporal_store(v, (f32x4*)(gbase + (size_t)row * NROWS + lane * 4));
            }
            // next loop-top BAR orders these ds_reads before slab reuse
        }
    }
}

// Fallback GEMM (ws too small for fp8 copies): inline fp32->bf16 cast staging.
#define FBM 128
#define FBN 128
__global__ __launch_bounds__(256) void rbf_mfma_inline(
    const float* __restrict__ X, const float* __restrict__ X1,
    const float* __restrict__ xsq, const float* __restrict__ x1sq,
    float* __restrict__ out)
{
    __shared__ uint16_t As[FBM * 32];
    __shared__ uint16_t Bs[FBN * 32];

    const int t    = threadIdx.x;
    const int bm   = blockIdx.x;
    const int bn   = blockIdx.y;
    const int lane = t & 63;
    const int w    = t >> 6;
    const int wm   = w >> 1;
    const int wn   = w & 1;

    f32x4 acc[4][4];
    #pragma unroll
    for (int i = 0; i < 4; ++i)
        #pragma unroll
        for (int j = 0; j < 4; ++j)
            acc[i][j] = f32x4{0.f, 0.f, 0.f, 0.f};

    const int lrow = lane & 15;
    const int kq   = (lane >> 4) * 8;
    int aoff[4], boff[4];
    #pragma unroll
    for (int i = 0; i < 4; ++i) {
        aoff[i] = (wm * 64 + i * 16 + lrow) * 32 + kq;
        boff[i] = (wn * 64 + i * 16 + lrow) * 32 + kq;
    }

    #pragma unroll 1
    for (int kt = 0; kt < DIMK / 32; ++kt) {
        #pragma unroll
        for (int i = 0; i < 4; ++i) {
            const int g   = t + i * 256;
            const int row = g >> 3;
            const int c4  = (g & 7) * 4;
            float4 va = *(const float4*)&X [(size_t)(bm * FBM + row) * DIMK + kt * 32 + c4];
            float4 vb = *(const float4*)&X1[(size_t)(bn * FBN + row) * DIMK + kt * 32 + c4];
            uint2 pa, pb;
            pa.x = f2bf(va.x) | (f2bf(va.y) << 16);
            pa.y = f2bf(va.z) | (f2bf(va.w) << 16);
            pb.x = f2bf(vb.x) | (f2bf(vb.y) << 16);
            pb.y = f2bf(vb.z) | (f2bf(vb.w) << 16);
            *(uint2*)&As[g * 4] = pa;
            *(uint2*)&Bs[g * 4] = pb;
        }
        __syncthreads();

        bf16x8 af[4], bg[4];
        #pragma unroll
        for (int i = 0; i < 4; ++i) af[i] = *(const bf16x8*)&As[aoff[i]];
        #pragma unroll
        for (int i = 0; i < 4; ++i) bg[i] = *(const bf16x8*)&Bs[boff[i]];
        #pragma unroll
        for (int i = 0; i < 4; ++i)
            #pragma unroll
            for (int j = 0; j < 4; ++j)
                acc[i][j] = __builtin_amdgcn_mfma_f32_16x16x32_bf16(af[i], bg[j], acc[i][j], 0, 0, 0);
        __syncthreads();
    }

    const int row0 = bm * FBM + wm * 64 + (lane >> 4) * 4;
    const int col0 = bn * FBN + wn * 64 + lrow;
    float xs[4][4], x1s[4];
    #pragma unroll
    for (int tm = 0; tm < 4; ++tm)
        #pragma unroll
        for (int r = 0; r < 4; ++r) xs[tm][r] = xsq[row0 + tm * 16 + r];
    #pragma unroll
    for (int tn = 0; tn < 4; ++tn) x1s[tn] = x1sq[col0 + tn * 16];

    #pragma unroll
    for (int tm = 0; tm < 4; ++tm)
        #pragma unroll
        for (int tn = 0; tn < 4; ++tn)
            #pragma unroll
            for (int r = 0; r < 4; ++r) {
                const int row = row0 + tm * 16 + r;
                const int col = col0 + tn * 16;
                float d = xs[tm][r] + x1s[tn] - 2.0f * acc[tm][tn][r];
                d = fmaxf(d, 0.0f);
                out[(size_t)row * NROWS + col] = __expf(-d);
            }
}

// ------------------------------------------------------------------ launch ---
extern "C" void kernel_launch(void* const* d_in, const int* in_sizes, int n_in,
                              void* d_out, int out_size, void* d_ws, size_t ws_size,
                              hipStream_t stream)
{
    const float* x  = (const float*)d_in[0];
    const float* x1 = (const float*)d_in[1];
    float* out = (float*)d_out;

    const size_t f8_bytes  = (size_t)NROWS * DIMK;                       // 4 MB each
    const size_t need_full = 2 * f8_bytes + 2 * (size_t)NROWS * sizeof(float);

    if (ws_size >= need_full) {
        uint8_t* xf   = (uint8_t*)d_ws;
        uint8_t* x1f  = xf + f8_bytes;
        float*   xsq  = (float*)((char*)d_ws + 2 * f8_bytes);
        float*   x1sq = xsq + NROWS;
        precast_fp8<<<dim3(NROWS / 4, 2), 256, 0, stream>>>(x, x1, xf, x1f, xsq, x1sq);
        rbf_stream_mxfp8<<<NROWS / 32, 512, 0, stream>>>(xf, x1f, xsq, x1sq, out);
    } else {
        float* xsq  = (float*)d_ws;       // 64 KB fallback
        float* x1sq = xsq + NROWS;
        norms_only<<<dim3(NROWS, 2), 256, 0, stream>>>(x, x1, xsq, x1sq);
        rbf_mfma_inline<<<dim3(NROWS / FBM, NROWS / FBN), 256, 0, stream>>>(x, x1, xsq, x1sq, out);
    }
}

// Round 11
// 295.360 us; speedup vs baseline: 1.3672x; 1.3672x over previous
//
#include <hip/hip_runtime.h>
#include <stdint.h>
#include <stddef.h>

// RBF kernel: out[i][j] = exp(-max(||x_i||^2 + ||x1_j||^2 - 2*x_i.x1_j, 0) / 1.0)
// N = M = 8192, K = 512, fp32 in/out.
//
// Round 16 = REVERT to the verified-best R3 kernel (bench 295.4us).
// Calibration from R8/R10 (both profiled + benched): bench = precast(13) +
// GEMM + 216 fixed harness overhead. Therefore R3's GEMM ~= 66us -- the NT
// stores + XCD stripe swizzle DID collapse it from R1's 287 (FETCH <=160MB
// implied). Every later restructure (256^2=88, bm-fast=90, persistent=97,
// streaming=175) was worse. GEMM write-roofline ~= 47us; R3 is at 72% of it
// and the bench floor is ~276 vs 295.4 -- remaining headroom ~6%, resisted
// by 7 structural attempts. This is the keeper.

#define NROWS 8192
#define DIMK  512
#define BM    128
#define BN    128
#define BKB   128              // K-bytes (= elements) per fp8 tile
#define KT    (DIMK / BKB)     // 4

typedef __bf16 bf16x8 __attribute__((ext_vector_type(8)));
typedef int    i32x8  __attribute__((ext_vector_type(8)));
typedef int    i32x4  __attribute__((ext_vector_type(4)));
typedef float  f32x4  __attribute__((ext_vector_type(4)));

#define AS1 __attribute__((address_space(1)))
#define AS3 __attribute__((address_space(3)))

// raw waits/barrier -- keep prefetch DMA in flight across barriers
#define WAITV(n) asm volatile("s_waitcnt vmcnt(" #n ")" ::: "memory")
#define WAITL()  asm volatile("s_waitcnt lgkmcnt(0)" ::: "memory")
#define BAR()    asm volatile("s_barrier" ::: "memory")

__device__ __forceinline__ uint32_t f2bf(float f) {
    uint32_t u = __float_as_uint(f);
    return (u + 0x7FFFu + ((u >> 16) & 1u)) >> 16;
}

// pack 4 floats -> 4 e4m3 bytes via HW converter (RNE, saturating)
__device__ __forceinline__ uint32_t pk_fp8x4(float a, float b, float c, float d) {
    int w = __builtin_amdgcn_cvt_pk_fp8_f32(a, b, 0, false);   // bytes 0,1
    w     = __builtin_amdgcn_cvt_pk_fp8_f32(c, d, w, true);    // bytes 2,3
    return (uint32_t)w;
}

// assemble a 32B MFMA fragment from two (swizzle-permuted) 16B LDS chunks
__device__ __forceinline__ i32x8 ld_frag(const uint8_t* base, int c_lo, int c_hi) {
    i32x4 lo = *(const i32x4*)(base + c_lo);
    i32x4 hi = *(const i32x4*)(base + c_hi);
    i32x8 r;
    r[0] = lo[0]; r[1] = lo[1]; r[2] = lo[2]; r[3] = lo[3];
    r[4] = hi[0]; r[5] = hi[1]; r[6] = hi[2]; r[7] = hi[3];
    return r;
}

// ---------------------------------------------------------------- precast ---
__global__ __launch_bounds__(256) void precast_fp8(
    const float* __restrict__ x, const float* __restrict__ x1,
    uint8_t* __restrict__ xf, uint8_t* __restrict__ x1f,
    float* __restrict__ xsq, float* __restrict__ x1sq)
{
    const int w    = threadIdx.x >> 6;
    const int lane = threadIdx.x & 63;
    const int row  = blockIdx.x * 4 + w;
    const float* src;
    uint8_t* dstb;
    float* dsts;
    if (blockIdx.y == 0) { src = x  + (size_t)row * DIMK; dstb = xf  + (size_t)row * DIMK; dsts = xsq  + row; }
    else                 { src = x1 + (size_t)row * DIMK; dstb = x1f + (size_t)row * DIMK; dsts = x1sq + row; }

    float4 v0 = ((const float4*)src)[lane * 2];
    float4 v1 = ((const float4*)src)[lane * 2 + 1];
    float s = v0.x * v0.x + v0.y * v0.y + v0.z * v0.z + v0.w * v0.w
            + v1.x * v1.x + v1.y * v1.y + v1.z * v1.z + v1.w * v1.w;

    uint2 p;
    p.x = pk_fp8x4(v0.x, v0.y, v0.z, v0.w);
    p.y = pk_fp8x4(v1.x, v1.y, v1.z, v1.w);
    ((uint2*)dstb)[lane] = p;

    #pragma unroll
    for (int off = 32; off > 0; off >>= 1) s += __shfl_down(s, off);
    if (lane == 0) *dsts = s;
}

// norms only (fallback path)
__global__ __launch_bounds__(256) void norms_only(
    const float* __restrict__ x, const float* __restrict__ x1,
    float* __restrict__ xsq, float* __restrict__ x1sq)
{
    const int row = blockIdx.x;
    const float* src = (blockIdx.y == 0) ? x + (size_t)row * DIMK : x1 + (size_t)row * DIMK;
    float* dsts      = (blockIdx.y == 0) ? xsq + row : x1sq + row;
    const int t = threadIdx.x;
    float2 v = ((const float2*)src)[t];
    float s = v.x * v.x + v.y * v.y;
    #pragma unroll
    for (int off = 32; off > 0; off >>= 1) s += __shfl_down(s, off);
    __shared__ float red[4];
    if ((t & 63) == 0) red[t >> 6] = s;
    __syncthreads();
    if (t == 0) *dsts = red[0] + red[1] + red[2] + red[3];
}

// ------------------------------------------- main GEMM (MX-fp8, pipelined) ---
// LDS map (single array; compiler can't reorder): [0,16K)=A buf0,
// [16K,32K)=A buf1, [32K,48K)=B buf0, [48K,64K)=B buf1.
// Epilogue scratch reuses [0,16K) (A buf0): last read at kt=2, and every
// wave has passed the kt=3 vmcnt(0)+barrier before any scratch write.
//
// Wait ladder (8 DMA loads per stage, vmcnt completes in order):
//   prologue: stage(0->b0), stage(1->b1)      [16 outstanding]
//   kt=0: vmcnt(8)+bar | reads | lgkm+bar | stage(2->b0) | mfma
//   kt=1: vmcnt(8)+bar | reads | lgkm+bar | stage(3->b1) | mfma
//   kt=2: vmcnt(8)+bar | reads |                         | mfma
//   kt=3: vmcnt(0)+bar | reads |                         | mfma
//
// Grid: 1D, 4096 blocks. XCD-chunked swizzle: xcd = id&7 owns the 8-wide
// bn-stripe [xcd*8, xcd*8+8); bn fastest within the stripe.
__global__ __launch_bounds__(256) void rbf_mfma_mxfp8(
    const uint8_t* __restrict__ Xf, const uint8_t* __restrict__ X1f,
    const float* __restrict__ xsq, const float* __restrict__ x1sq,
    float* __restrict__ out)
{
    __shared__ uint8_t lds[65536];

    const int t    = threadIdx.x;
    const int id   = blockIdx.x;
    const int xcd  = id & 7;
    const int loc  = id >> 3;                 // 0..511 within the XCD
    const int bm   = loc >> 3;                // 0..63, slow
    const int bn   = (xcd << 3) | (loc & 7);  // stripe column, fast
    const int lane = t & 63;
    const int w    = t >> 6;
    const int wm   = w >> 1;
    const int wn   = w & 1;

    const int srow   = t >> 3;                       // 0..31
    const int schunk = (t & 7) ^ (srow & 7);         // XOR-swizzled global chunk
    const uint8_t* gA = Xf  + (size_t)(bm * BM + srow) * DIMK + schunk * 16;
    const uint8_t* gB = X1f + (size_t)(bn * BN + srow) * DIMK + schunk * 16;

    f32x4 acc[4][4];   // acc[tn][tm]
    #pragma unroll
    for (int i = 0; i < 4; ++i)
        #pragma unroll
        for (int j = 0; j < 4; ++j)
            acc[i][j] = f32x4{0.f, 0.f, 0.f, 0.f};

    // Operand layout (A and B identical): row = lane&15, kbyte = q*32+0..31.
    // Staging swizzle: kbyte chunk c of row r lives at LDS chunk c^(r&7).
    const int lrow = lane & 15;
    const int q    = lane >> 4;
    const int s    = lrow & 7;
    const int c_lo = ((2 * q)     ^ s) * 16;
    const int c_hi = ((2 * q + 1) ^ s) * 16;
    int roff[4];
    #pragma unroll
    for (int i = 0; i < 4; ++i) roff[i] = (i * 16 + lrow) * BKB;

    auto stage = [&](int kt, int b) {
        const uint8_t* ga = gA + kt * BKB;
        const uint8_t* gb = gB + kt * BKB;
        uint8_t* la = &lds[b * 16384 + t * 16];
        uint8_t* lb = &lds[32768 + b * 16384 + t * 16];
        #pragma unroll
        for (int c = 0; c < 4; ++c) {
            __builtin_amdgcn_global_load_lds((AS1 void*)(ga + (size_t)c * 32 * DIMK),
                                             (AS3 void*)(la + c * 4096), 16, 0, 0);
            __builtin_amdgcn_global_load_lds((AS1 void*)(gb + (size_t)c * 32 * DIMK),
                                             (AS3 void*)(lb + c * 4096), 16, 0, 0);
        }
    };

    auto read_frags = [&](int b, i32x8* af, i32x8* bg) {
        const uint8_t* Ab = &lds[b * 16384 + wm * 64 * BKB];
        const uint8_t* Bb = &lds[32768 + b * 16384 + wn * 64 * BKB];
        #pragma unroll
        for (int i = 0; i < 4; ++i) af[i] = ld_frag(Ab + roff[i], c_lo, c_hi);
        #pragma unroll
        for (int i = 0; i < 4; ++i) bg[i] = ld_frag(Bb + roff[i], c_lo, c_hi);
    };

    // swapped operands: A = bg[tn] (x1 rows -> reg dim), B = af[tm] (x rows
    // -> lane&15 dim). Lane holds out-row = lrow, out-cols = q*4+reg.
    auto do_mfma = [&](const i32x8* af, const i32x8* bg) {
        #pragma unroll
        for (int j = 0; j < 4; ++j)
            #pragma unroll
            for (int i = 0; i < 4; ++i)
                acc[j][i] = __builtin_amdgcn_mfma_scale_f32_16x16x128_f8f6f4(
                    bg[j], af[i], acc[j][i],
                    0, 0,                    // cbsz=0 (fp8 e4m3), blgp=0 (fp8 e4m3)
                    0, 0x7F7F7F7F,           // opselA, scaleA (e8m0 127 = 2^0)
                    0, 0x7F7F7F7F);          // opselB, scaleB
    };

    i32x8 af[4], bg[4];

    stage(0, 0);
    stage(1, 1);                           // 16 outstanding

    // kt = 0
    WAITV(8); BAR();
    read_frags(0, af, bg);
    WAITL(); BAR();
    stage(2, 0);
    do_mfma(af, bg);

    // kt = 1
    WAITV(8); BAR();
    read_frags(1, af, bg);
    WAITL(); BAR();
    stage(3, 1);
    do_mfma(af, bg);

    // kt = 2
    WAITV(8); BAR();
    read_frags(0, af, bg);
    do_mfma(af, bg);

    // kt = 3
    WAITV(0); BAR();
    read_frags(1, af, bg);
    do_mfma(af, bg);

    // ------------------------------------------------------------ epilogue ---
    // Wave-private 4KB scratch in [0,16K): wave w at w*4096. Per tm, the wave
    // round-trips its 16x64 fp32 sub-tile through LDS so each NT
    // global_store_dwordx4 covers 4 rows x 256B contiguous (full 128B lines).
    // XOR chunk swizzle (lc ^ (row&7)) spreads both LDS phases over all banks.
    // No barrier needed: scratch is wave-private; per-wave DS ops are ordered.
    const int orow_w = bm * BM + wm * 64;            // wave's out-row base
    const int ocol_w = bn * BN + wn * 64;            // wave's out-col base
    uint8_t* scr = &lds[w * 4096];

    // producer-side norms: row norm for this lane's out-row, col norms x4
    float xsl[4];
    f32x4 x1v[4];
    #pragma unroll
    for (int tm = 0; tm < 4; ++tm) xsl[tm] = xsq[orow_w + tm * 16 + lrow];
    #pragma unroll
    for (int tn = 0; tn < 4; ++tn) x1v[tn] = *(const f32x4*)&x1sq[ocol_w + tn * 16 + q * 4];

    // consumer-side lane mapping: 16 lanes per row, 4 rows per store inst
    const int crow = lane >> 4;          // 0..3 (row within a 4-row store)
    const int clc  = lane & 15;          // 16B chunk within the 64-col row

    #pragma unroll
    for (int tm = 0; tm < 4; ++tm) {
        // produce: value(row=lrow, col = tn*16 + q*4 + r)
        #pragma unroll
        for (int tn = 0; tn < 4; ++tn) {
            f32x4 a = acc[tn][tm];
            f32x4 ev;
            #pragma unroll
            for (int r = 0; r < 4; ++r) {
                float d = fmaxf(xsl[tm] + x1v[tn][r] - 2.0f * a[r], 0.0f);
                ev[r] = __expf(-d);
            }
            const int lc = tn * 4 + q;                         // logical chunk
            *(f32x4*)(scr + lrow * 256 + ((lc ^ s) * 16)) = ev;
        }
        // consume: 4 store insts, each 4 rows x 16 chunks = 1KB contiguous/row-group
        float* gbase = out + (size_t)(orow_w + tm * 16) * NROWS + ocol_w;
        #pragma unroll
        for (int si = 0; si < 4; ++si) {
            const int row = si * 4 + crow;
            f32x4 v = *(const f32x4*)(scr + row * 256 + ((clc ^ (row & 7)) * 16));
            __builtin_nontemporal_store(v, (f32x4*)(gbase + (size_t)row * NROWS + clc * 4));
        }
    }
}

// Fallback GEMM (ws too small for fp8 copies): inline fp32->bf16 cast staging.
#define FBM 128
#define FBN 128
__global__ __launch_bounds__(256) void rbf_mfma_inline(
    const float* __restrict__ X, const float* __restrict__ X1,
    const float* __restrict__ xsq, const float* __restrict__ x1sq,
    float* __restrict__ out)
{
    __shared__ uint16_t As[FBM * 32];
    __shared__ uint16_t Bs[FBN * 32];

    const int t    = threadIdx.x;
    const int bm   = blockIdx.x;
    const int bn   = blockIdx.y;
    const int lane = t & 63;
    const int w    = t >> 6;
    const int wm   = w >> 1;
    const int wn   = w & 1;

    f32x4 acc[4][4];
    #pragma unroll
    for (int i = 0; i < 4; ++i)
        #pragma unroll
        for (int j = 0; j < 4; ++j)
            acc[i][j] = f32x4{0.f, 0.f, 0.f, 0.f};

    const int lrow = lane & 15;
    const int kq   = (lane >> 4) * 8;
    int aoff[4], boff[4];
    #pragma unroll
    for (int i = 0; i < 4; ++i) {
        aoff[i] = (wm * 64 + i * 16 + lrow) * 32 + kq;
        boff[i] = (wn * 64 + i * 16 + lrow) * 32 + kq;
    }

    #pragma unroll 1
    for (int kt = 0; kt < DIMK / 32; ++kt) {
        #pragma unroll
        for (int i = 0; i < 4; ++i) {
            const int g   = t + i * 256;
            const int row = g >> 3;
            const int c4  = (g & 7) * 4;
            float4 va = *(const float4*)&X [(size_t)(bm * FBM + row) * DIMK + kt * 32 + c4];
            float4 vb = *(const float4*)&X1[(size_t)(bn * FBN + row) * DIMK + kt * 32 + c4];
            uint2 pa, pb;
            pa.x = f2bf(va.x) | (f2bf(va.y) << 16);
            pa.y = f2bf(va.z) | (f2bf(va.w) << 16);
            pb.x = f2bf(vb.x) | (f2bf(vb.y) << 16);
            pb.y = f2bf(vb.z) | (f2bf(vb.w) << 16);
            *(uint2*)&As[g * 4] = pa;
            *(uint2*)&Bs[g * 4] = pb;
        }
        __syncthreads();

        bf16x8 af[4], bg[4];
        #pragma unroll
        for (int i = 0; i < 4; ++i) af[i] = *(const bf16x8*)&As[aoff[i]];
        #pragma unroll
        for (int i = 0; i < 4; ++i) bg[i] = *(const bf16x8*)&Bs[boff[i]];
        #pragma unroll
        for (int i = 0; i < 4; ++i)
            #pragma unroll
            for (int j = 0; j < 4; ++j)
                acc[i][j] = __builtin_amdgcn_mfma_f32_16x16x32_bf16(af[i], bg[j], acc[i][j], 0, 0, 0);
        __syncthreads();
    }

    const int row0 = bm * FBM + wm * 64 + (lane >> 4) * 4;
    const int col0 = bn * FBN + wn * 64 + lrow;
    float xs[4][4], x1s[4];
    #pragma unroll
    for (int tm = 0; tm < 4; ++tm)
        #pragma unroll
        for (int r = 0; r < 4; ++r) xs[tm][r] = xsq[row0 + tm * 16 + r];
    #pragma unroll
    for (int tn = 0; tn < 4; ++tn) x1s[tn] = x1sq[col0 + tn * 16];

    #pragma unroll
    for (int tm = 0; tm < 4; ++tm)
        #pragma unroll
        for (int tn = 0; tn < 4; ++tn)
            #pragma unroll
            for (int r = 0; r < 4; ++r) {
                const int row = row0 + tm * 16 + r;
                const int col = col0 + tn * 16;
                float d = xs[tm][r] + x1s[tn] - 2.0f * acc[tm][tn][r];
                d = fmaxf(d, 0.0f);
                out[(size_t)row * NROWS + col] = __expf(-d);
            }
}

// ------------------------------------------------------------------ launch ---
extern "C" void kernel_launch(void* const* d_in, const int* in_sizes, int n_in,
                              void* d_out, int out_size, void* d_ws, size_t ws_size,
                              hipStream_t stream)
{
    const float* x  = (const float*)d_in[0];
    const float* x1 = (const float*)d_in[1];
    float* out = (float*)d_out;

    const size_t f8_bytes  = (size_t)NROWS * DIMK;                       // 4 MB each
    const size_t need_full = 2 * f8_bytes + 2 * (size_t)NROWS * sizeof(float);

    if (ws_size >= need_full) {
        uint8_t* xf   = (uint8_t*)d_ws;
        uint8_t* x1f  = xf + f8_bytes;
        float*   xsq  = (float*)((char*)d_ws + 2 * f8_bytes);
        float*   x1sq = xsq + NROWS;
        precast_fp8<<<dim3(NROWS / 4, 2), 256, 0, stream>>>(x, x1, xf, x1f, xsq, x1sq);
        rbf_mfma_mxfp8<<<(NROWS / BM) * (NROWS / BN), 256, 0, stream>>>(xf, x1f, xsq, x1sq, out);
    } else {
        float* xsq  = (float*)d_ws;       // 64 KB fallback
        float* x1sq = xsq + NROWS;
        norms_only<<<dim3(NROWS, 2), 256, 0, stream>>>(x, x1, xsq, x1sq);
        rbf_mfma_inline<<<dim3(NROWS / FBM, NROWS / FBN), 256, 0, stream>>>(x, x1, xsq, x1sq, out);
    }
}